// Round 4
// baseline (680.011 us; speedup 1.0000x reference)
//
#include <hip/hip_runtime.h>
#include <hip/hip_bf16.h>

#define Bn 32
#define Ln 1024
#define En 512
#define On 512

typedef __attribute__((ext_vector_type(8))) short bf16x8;
typedef __attribute__((ext_vector_type(4))) float f32x4;

__device__ __forceinline__ ushort f2bf(float x) {
    __hip_bfloat16 h = __float2bfloat16(x);
    return *reinterpret_cast<ushort*>(&h);
}
__device__ __forceinline__ float bf2f(ushort u) {
    __hip_bfloat16 h;
    *reinterpret_cast<ushort*>(&h) = u;
    return __bfloat162float(h);
}

__device__ __forceinline__ f32x4 mfma_bf16(bf16x8 a, bf16x8 b, f32x4 c) {
    return __builtin_amdgcn_mfma_f32_16x16x32_bf16(a, b, c, 0, 0, 0);
}

// ---------------------------------------------------------------------------
// Shared NT bf16 GEMM core: 128x128 tile, BK=32, 256 threads (4 waves 2x2),
// operands in [idx][k] layout (A row idx = out row, B row idx = out col).
// acc[m][n] C-layout: col = ln (lane&15), row = (lane>>4)*4 + r.
// ---------------------------------------------------------------------------
template <int ASTRIDE, int BSTRIDE>
__device__ __forceinline__ void nt_bf16_gemm(const ushort* __restrict__ Abase,
                                             const ushort* __restrict__ Bbase,
                                             int Kd, f32x4 (&acc)[4][4]) {
    __shared__ short sA[128][40], sB[128][40];
    const int tid = threadIdx.x;
    const int lane = tid & 63, wave = tid >> 6;
    const int wr = (wave >> 1) * 64, wc = (wave & 1) * 64;
    const int ln = lane & 15, kb = (lane >> 4) * 8;

    for (int k0 = 0; k0 < Kd; k0 += 32) {
#pragma unroll
        for (int cc = 0; cc < 2; ++cc) {
            const int c = tid + cc * 256;
            const int row = c >> 2, col = (c & 3) * 8;
            *(bf16x8*)&sA[row][col] = *(const bf16x8*)(Abase + (size_t)row * ASTRIDE + k0 + col);
            *(bf16x8*)&sB[row][col] = *(const bf16x8*)(Bbase + (size_t)row * BSTRIDE + k0 + col);
        }
        __syncthreads();
        bf16x8 bfr[4];
#pragma unroll
        for (int n = 0; n < 4; ++n) bfr[n] = *(bf16x8*)&sB[wc + n * 16 + ln][kb];
#pragma unroll
        for (int m = 0; m < 4; ++m) {
            bf16x8 a = *(bf16x8*)&sA[wr + m * 16 + ln][kb];
#pragma unroll
            for (int n = 0; n < 4; ++n) acc[m][n] = mfma_bf16(a, bfr[n], acc[m][n]);
        }
        __syncthreads();
    }
}

// ---------------------------------------------------------------------------
// W [E,O] fp32 -> wtcat[z][n][k'] bf16, k' (1536) = [Whi | Whi | Wlo]
// (B-side concat layout so that A=[hi|lo|hi] gives hh + lh + hl terms)
// ---------------------------------------------------------------------------
__global__ __launch_bounds__(256) void convert_w(const float* __restrict__ Wq,
                                                 const float* __restrict__ Wk,
                                                 const float* __restrict__ Wv,
                                                 ushort* __restrict__ wtcat) {
    const int z = blockIdx.z;
    const float* W = (z == 0) ? Wq : (z == 1) ? Wk : Wv;
    ushort* base = wtcat + (size_t)z * On * 1536;  // [n][1536]
    __shared__ float tile[32][33];
    const int n0 = blockIdx.x * 32, k0 = blockIdx.y * 32;
    const int tid = threadIdx.x;
    const int r = tid >> 3, c4 = (tid & 7) * 4;
    float4 wv = *(const float4*)&W[(size_t)(k0 + r) * On + n0 + c4];
    tile[r][c4 + 0] = wv.x;
    tile[r][c4 + 1] = wv.y;
    tile[r][c4 + 2] = wv.z;
    tile[r][c4 + 3] = wv.w;
    __syncthreads();
    ushort4 hs, ls;
    ushort* hp = &hs.x;
    ushort* lp = &ls.x;
#pragma unroll
    for (int jj = 0; jj < 4; ++jj) {
        float f = tile[c4 + jj][r];
        ushort h = f2bf(f);
        hp[jj] = h;
        lp[jj] = f2bf(f - bf2f(h));
    }
    ushort* rowp = base + (size_t)(n0 + r) * 1536;
    *(ushort4*)&rowp[k0 + c4] = hs;
    *(ushort4*)&rowp[512 + k0 + c4] = hs;
    *(ushort4*)&rowp[1024 + k0 + c4] = ls;
}

// ---------------------------------------------------------------------------
// X [32768, 512] fp32 -> Xcat [32768, 1536] bf16, k' = [Xhi | Xlo | Xhi]
// ---------------------------------------------------------------------------
__global__ __launch_bounds__(256) void convert_x(const float* __restrict__ X,
                                                 ushort* __restrict__ Xcat) {
    const int g = blockIdx.x * 256 + threadIdx.x;
    const int row = g >> 6;
    const int k0 = (g & 63) * 8;
    const float* xp = X + (size_t)row * En + k0;
    float4 x0 = *(const float4*)xp;
    float4 x1 = *(const float4*)(xp + 4);
    float xs[8] = {x0.x, x0.y, x0.z, x0.w, x1.x, x1.y, x1.z, x1.w};
    bf16x8 hi, lo;
#pragma unroll
    for (int j = 0; j < 8; ++j) {
        ushort h = f2bf(xs[j]);
        hi[j] = (short)h;
        lo[j] = (short)f2bf(xs[j] - bf2f(h));
    }
    ushort* op = Xcat + (size_t)row * 1536 + k0;
    *(bf16x8*)op = hi;
    *(bf16x8*)(op + 512) = lo;
    *(bf16x8*)(op + 1024) = hi;
}

// ---------------------------------------------------------------------------
// Pass 1: [Q|K|V] = Xcat * wtcat^T  (plain bf16 NT, K'=1536)
// grid 3072 linear with XCD swizzle. z==0: Qcat [hi|lo|hi]; z==1: Kcat
// [hi|hi|lo]; z==2: vt[b][o][l] bf16.
// ---------------------------------------------------------------------------
__global__ __launch_bounds__(256) void gemm_qkv(const ushort* __restrict__ Xcat,
                                                const ushort* __restrict__ wtcat,
                                                ushort* __restrict__ Qcat,
                                                ushort* __restrict__ Kcat,
                                                ushort* __restrict__ vt) {
    const int n = blockIdx.x;
    const int xcd = n & 7;
    const int r = n >> 3;
    const int x = r % 12;
    const int y = (r / 12) * 8 + xcd;
    const int row0 = y * 128;
    const int col0 = x * 128;
    const int z = col0 >> 9;
    const int wcol = col0 & 511;

    f32x4 acc[4][4] = {};
    nt_bf16_gemm<1536, 1536>(Xcat + (size_t)row0 * 1536,
                             wtcat + ((size_t)z * On + wcol) * 1536, 1536, acc);

    const int tid = threadIdx.x;
    const int lane = tid & 63, wave = tid >> 6;
    const int wr = (wave >> 1) * 64, wc = (wave & 1) * 64;
    const int ln = lane & 15;

    if (z < 2) {
#pragma unroll
        for (int m = 0; m < 4; ++m)
#pragma unroll
            for (int nn = 0; nn < 4; ++nn)
#pragma unroll
                for (int rr = 0; rr < 4; ++rr) {
                    const int gi = row0 + wr + m * 16 + (lane >> 4) * 4 + rr;
                    const int gj = wcol + wc + nn * 16 + ln;
                    const float v = acc[m][nn][rr];
                    const ushort h = f2bf(v);
                    const ushort l = f2bf(v - bf2f(h));
                    ushort* rp = ((z == 0) ? Qcat : Kcat) + (size_t)gi * 1536;
                    if (z == 0) {  // A-side: [hi | lo | hi]
                        rp[gj] = h;
                        rp[512 + gj] = l;
                        rp[1024 + gj] = h;
                    } else {  // B-side: [hi | hi | lo]
                        rp[gj] = h;
                        rp[512 + gj] = h;
                        rp[1024 + gj] = l;
                    }
                }
    } else {
        const int b = row0 >> 10;
        const int lbase = row0 & (Ln - 1);
#pragma unroll
        for (int m = 0; m < 4; ++m)
#pragma unroll
            for (int nn = 0; nn < 4; ++nn) {
                const int gj = wcol + wc + nn * 16 + ln;               // o
                const int l0 = lbase + wr + m * 16 + (lane >> 4) * 4;  // l
                ushort4 u;
                u.x = f2bf(acc[m][nn][0]);
                u.y = f2bf(acc[m][nn][1]);
                u.z = f2bf(acc[m][nn][2]);
                u.w = f2bf(acc[m][nn][3]);
                *(ushort4*)(vt + ((size_t)b * On + gj) * Ln + l0) = u;
            }
    }
}

// ---------------------------------------------------------------------------
// Pass 2: S[b] = Qcat[b] * Kcat[b]^T (K'=1536) + sum_k delta -> fp32
// grid 2048 linear; batch b -> XCD b%8.
// ---------------------------------------------------------------------------
__global__ __launch_bounds__(256) void gemm_scores(const ushort* __restrict__ Qcat,
                                                   const ushort* __restrict__ Kcat,
                                                   const float* __restrict__ delta,
                                                   float* __restrict__ S) {
    const int n = blockIdx.x;
    const int xcd = n & 7;
    const int c = n >> 3;
    const int b = (c / 64) * 8 + xcd;
    const int xy = c % 64;
    const int col0 = (xy & 7) * 128;
    const int row0 = (xy >> 3) * 128;

    f32x4 acc[4][4] = {};
    nt_bf16_gemm<1536, 1536>(Qcat + ((size_t)b * Ln + row0) * 1536,
                             Kcat + ((size_t)b * Ln + col0) * 1536, 1536, acc);

    const int tid = threadIdx.x;
    const int lane = tid & 63, wave = tid >> 6;
    const int wr = (wave >> 1) * 64, wc = (wave & 1) * 64;
    const int ln = lane & 15;

#pragma unroll
    for (int m = 0; m < 4; ++m)
#pragma unroll
        for (int nn = 0; nn < 4; ++nn)
#pragma unroll
            for (int rr = 0; rr < 4; ++rr) {
                const int gi = row0 + wr + m * 16 + (lane >> 4) * 4 + rr;
                const int gj = col0 + wc + nn * 16 + ln;
                const float4 dv = *(const float4*)(delta + (((size_t)b * Ln + gi) * Ln + gj) * 4);
                S[((size_t)b * Ln + gi) * Ln + gj] = acc[m][nn][rr] + ((dv.x + dv.y) + (dv.z + dv.w));
            }
}

// ---------------------------------------------------------------------------
// Pass 3: full-row softmax (denom over ALL j), post-softmax mask,
// P written bf16 in place (first 2048B of each 4KB S row).
// ---------------------------------------------------------------------------
__global__ __launch_bounds__(256) void softmax_kernel(float* __restrict__ S,
                                                      const int* __restrict__ traj) {
    const int row = blockIdx.x;  // b*L + i
    const int b = row >> 10;
    const int i = row & (Ln - 1);
    const int t = traj[b];
    float* Srow = S + (size_t)row * Ln;
    ushort* Prow = (ushort*)Srow;
    const int tid = threadIdx.x;
    const int j0 = tid * 4;

    if (i >= t) {
        ushort4 z = {0, 0, 0, 0};
        *(ushort4*)&Prow[j0] = z;
        return;
    }

    float4 v = *(const float4*)&Srow[j0];
    __shared__ float red[4];

    float m = fmaxf(fmaxf(v.x, v.y), fmaxf(v.z, v.w));
#pragma unroll
    for (int off = 32; off >= 1; off >>= 1) m = fmaxf(m, __shfl_xor(m, off));
    if ((tid & 63) == 0) red[tid >> 6] = m;
    __syncthreads();
    m = fmaxf(fmaxf(red[0], red[1]), fmaxf(red[2], red[3]));
    __syncthreads();

    float e0 = expf(v.x - m), e1 = expf(v.y - m), e2 = expf(v.z - m), e3 = expf(v.w - m);
    float s = (e0 + e1) + (e2 + e3);
#pragma unroll
    for (int off = 32; off >= 1; off >>= 1) s += __shfl_xor(s, off);
    if ((tid & 63) == 0) red[tid >> 6] = s;
    __syncthreads();
    s = (red[0] + red[1]) + (red[2] + red[3]);
    const float inv = 1.0f / s;

    ushort4 o;
    o.x = (j0 + 0 < t) ? f2bf(e0 * inv) : (ushort)0;
    o.y = (j0 + 1 < t) ? f2bf(e1 * inv) : (ushort)0;
    o.z = (j0 + 2 < t) ? f2bf(e2 * inv) : (ushort)0;
    o.w = (j0 + 3 < t) ? f2bf(e3 * inv) : (ushort)0;
    *(ushort4*)&Prow[j0] = o;
}

// ---------------------------------------------------------------------------
// Pass 4: out[b] = P[b] (bf16, row stride 2048) * V[b]  (K=1024)
// grid 1024 linear; batch b -> XCD b%8.
// ---------------------------------------------------------------------------
__global__ __launch_bounds__(256) void gemm_pv(const ushort* __restrict__ P,
                                               const ushort* __restrict__ vt,
                                               float* __restrict__ out) {
    const int n = blockIdx.x;
    const int xcd = n & 7;
    const int c = n >> 3;
    const int b = (c / 32) * 8 + xcd;
    const int xy = c % 32;
    const int col0 = (xy & 3) * 128;
    const int row0 = (xy >> 2) * 128;

    f32x4 acc[4][4] = {};
    nt_bf16_gemm<2048, 1024>(P + ((size_t)b * Ln + row0) * 2048,
                             vt + ((size_t)b * On + col0) * 1024, 1024, acc);

    const int tid = threadIdx.x;
    const int lane = tid & 63, wave = tid >> 6;
    const int wr = (wave >> 1) * 64, wc = (wave & 1) * 64;
    const int ln = lane & 15;

#pragma unroll
    for (int m = 0; m < 4; ++m)
#pragma unroll
        for (int nn = 0; nn < 4; ++nn)
#pragma unroll
            for (int rr = 0; rr < 4; ++rr) {
                const int gi = row0 + wr + m * 16 + (lane >> 4) * 4 + rr;
                const int gj = col0 + wc + nn * 16 + ln;
                out[((size_t)b * Ln + gi) * On + gj] = acc[m][nn][rr];
            }
}

extern "C" void kernel_launch(void* const* d_in, const int* in_sizes, int n_in,
                              void* d_out, int out_size, void* d_ws, size_t ws_size,
                              hipStream_t stream) {
    const float* X = (const float*)d_in[0];      // [B, L, E]
    const float* delta = (const float*)d_in[1];  // [B, L, L, 4]
    const float* Wq = (const float*)d_in[2];     // [E, O]
    const float* Wk = (const float*)d_in[3];
    const float* Wv = (const float*)d_in[4];
    const int* traj = (const int*)d_in[5];       // [B]
    float* out = (float*)d_out;

    // ws layout (ushort units unless noted)
    ushort* wtcat = (ushort*)d_ws;                     // 3 * 512 * 1536
    ushort* Xcat = wtcat + (size_t)3 * On * 1536;      // 32768 * 1536
    ushort* Qcat = Xcat + (size_t)Bn * Ln * 1536;      // 32768 * 1536
    ushort* Kcat = Qcat + (size_t)Bn * Ln * 1536;      // 32768 * 1536
    ushort* vt = Kcat + (size_t)Bn * Ln * 1536;        // [B][O][L]
    float* S = (float*)(vt + (size_t)Bn * Ln * On);    // [B][L][L] fp32 / P bf16 in place

    convert_w<<<dim3(On / 32, En / 32, 3), 256, 0, stream>>>(Wq, Wk, Wv, wtcat);
    convert_x<<<dim3((Bn * Ln * 64) / 256), 256, 0, stream>>>(X, Xcat);
    gemm_qkv<<<dim3(3072), 256, 0, stream>>>(Xcat, wtcat, Qcat, Kcat, vt);
    gemm_scores<<<dim3(2048), 256, 0, stream>>>(Qcat, Kcat, delta, S);
    softmax_kernel<<<dim3(Bn * Ln), 256, 0, stream>>>(S, traj);
    gemm_pv<<<dim3(1024), 256, 0, stream>>>((const ushort*)S, vt, out);
}

// Round 5
// 509.687 us; speedup vs baseline: 1.3342x; 1.3342x over previous
//
#include <hip/hip_runtime.h>
#include <hip/hip_bf16.h>

#define Bn 32
#define Ln 1024
#define En 512
#define On 512

typedef __attribute__((ext_vector_type(8))) short bf16x8;
typedef __attribute__((ext_vector_type(4))) float f32x4;

__device__ __forceinline__ ushort f2bf(float x) {
    __hip_bfloat16 h = __float2bfloat16(x);
    return *reinterpret_cast<ushort*>(&h);
}
__device__ __forceinline__ float bf2f(ushort u) {
    __hip_bfloat16 h;
    *reinterpret_cast<ushort*>(&h) = u;
    return __bfloat162float(h);
}

__device__ __forceinline__ f32x4 mfma_bf16(bf16x8 a, bf16x8 b, f32x4 c) {
    return __builtin_amdgcn_mfma_f32_16x16x32_bf16(a, b, c, 0, 0, 0);
}

// ---------------------------------------------------------------------------
// Stage a 128x32 bf16 tile (row stride `rstride` shorts) into linear LDS
// [128][32] via global_load_lds width=16. Dest must be linear: lds byte
// offset = chunk*16 where chunk c -> (row = c>>2, col = (c&3)*8 shorts).
// 256 threads * 2 issues * 16 B = 8 KB.
// ---------------------------------------------------------------------------
__device__ __forceinline__ void stage(ushort* dst, const ushort* src, size_t rstride) {
    const int tid = threadIdx.x;
#pragma unroll
    for (int cc = 0; cc < 2; ++cc) {
        const int c = tid + cc * 256;
        const ushort* g = src + (size_t)(c >> 2) * rstride + (c & 3) * 8;
        // wave-uniform LDS base: this wave's 64 chunks start at (wave*64 + cc*256)*8 shorts
        ushort* l = dst + ((size_t)(tid >> 6) * 64 + cc * 256) * 8;
        __builtin_amdgcn_global_load_lds(
            (const __attribute__((address_space(1))) unsigned int*)g,
            (__attribute__((address_space(3))) unsigned int*)l, 16, 0, 0);
    }
}

// ---------------------------------------------------------------------------
// NT bf16 GEMM core, 128x128 tile, BK=32, 256 threads (4 waves 2x2).
// SPLIT: A has hi/lo, B has hi/lo; acc += Ah*Bh + Ah*Bl + Al*Bh (3-term
// compensated product). Otherwise plain Ah*Bh.
// acc[m][n] C-layout: col = lane&15, row = (lane>>4)*4 + r.
// ---------------------------------------------------------------------------
template <bool SPLIT>
__device__ __forceinline__ void nt_core(const ushort* __restrict__ Ah,
                                        const ushort* __restrict__ Al,
                                        const ushort* __restrict__ Bh,
                                        const ushort* __restrict__ Bl,
                                        size_t astr, size_t bstr, int Kd,
                                        f32x4 (&acc)[4][4]) {
    __shared__ ushort lds[(SPLIT ? 4 : 2) * 4096];
    ushort* sAh = lds;
    ushort* sBh = lds + 4096;
    ushort* sAl = SPLIT ? lds + 8192 : nullptr;
    ushort* sBl = SPLIT ? lds + 12288 : nullptr;

    const int tid = threadIdx.x;
    const int lane = tid & 63, wave = tid >> 6;
    const int wr = (wave >> 1) * 64, wc = (wave & 1) * 64;
    const int ln = lane & 15, kb = (lane >> 4) * 8;

    for (int k0 = 0; k0 < Kd; k0 += 32) {
        stage(sAh, Ah + k0, astr);
        stage(sBh, Bh + k0, bstr);
        if constexpr (SPLIT) {
            stage(sAl, Al + k0, astr);
            stage(sBl, Bl + k0, bstr);
        }
        __syncthreads();
        bf16x8 bh[4], bl[4];
#pragma unroll
        for (int n = 0; n < 4; ++n) {
            bh[n] = *(bf16x8*)&sBh[(size_t)(wc + n * 16 + ln) * 32 + kb];
            if constexpr (SPLIT) bl[n] = *(bf16x8*)&sBl[(size_t)(wc + n * 16 + ln) * 32 + kb];
        }
#pragma unroll
        for (int m = 0; m < 4; ++m) {
            bf16x8 ah = *(bf16x8*)&sAh[(size_t)(wr + m * 16 + ln) * 32 + kb];
            if constexpr (SPLIT) {
                bf16x8 al = *(bf16x8*)&sAl[(size_t)(wr + m * 16 + ln) * 32 + kb];
#pragma unroll
                for (int n = 0; n < 4; ++n) {
                    acc[m][n] = mfma_bf16(ah, bh[n], acc[m][n]);
                    acc[m][n] = mfma_bf16(ah, bl[n], acc[m][n]);
                    acc[m][n] = mfma_bf16(al, bh[n], acc[m][n]);
                }
            } else {
#pragma unroll
                for (int n = 0; n < 4; ++n) acc[m][n] = mfma_bf16(ah, bh[n], acc[m][n]);
            }
        }
        __syncthreads();
    }
}

// ---------------------------------------------------------------------------
// W [E,O] fp32 -> per z: whi/wlo [n][k] bf16 (transposed), stride En.
// ---------------------------------------------------------------------------
__global__ __launch_bounds__(256) void convert_w(const float* __restrict__ Wq,
                                                 const float* __restrict__ Wk,
                                                 const float* __restrict__ Wv,
                                                 ushort* __restrict__ wsplit) {
    const int z = blockIdx.z;
    const float* W = (z == 0) ? Wq : (z == 1) ? Wk : Wv;
    ushort* hi = wsplit + (size_t)z * 2 * (En * On);
    ushort* lo = hi + En * On;
    __shared__ float tile[32][33];
    const int n0 = blockIdx.x * 32, k0 = blockIdx.y * 32;
    const int tid = threadIdx.x;
    const int r = tid >> 3, c4 = (tid & 7) * 4;
    float4 wv = *(const float4*)&W[(size_t)(k0 + r) * On + n0 + c4];
    tile[r][c4 + 0] = wv.x;
    tile[r][c4 + 1] = wv.y;
    tile[r][c4 + 2] = wv.z;
    tile[r][c4 + 3] = wv.w;
    __syncthreads();
    ushort4 hs, ls;
    ushort* hp = &hs.x;
    ushort* lp = &ls.x;
#pragma unroll
    for (int jj = 0; jj < 4; ++jj) {
        float f = tile[c4 + jj][r];
        ushort h = f2bf(f);
        hp[jj] = h;
        lp[jj] = f2bf(f - bf2f(h));
    }
    *(ushort4*)&hi[(size_t)(n0 + r) * En + k0 + c4] = hs;
    *(ushort4*)&lo[(size_t)(n0 + r) * En + k0 + c4] = ls;
}

// ---------------------------------------------------------------------------
// X [32768, 512] fp32 -> Xhi / Xlo [32768, 512] bf16
// ---------------------------------------------------------------------------
__global__ __launch_bounds__(256) void convert_x(const float* __restrict__ X,
                                                 ushort* __restrict__ Xhi,
                                                 ushort* __restrict__ Xlo) {
    const int g = blockIdx.x * 256 + threadIdx.x;
    const int row = g >> 6;
    const int k0 = (g & 63) * 8;
    const float* xp = X + (size_t)row * En + k0;
    float4 x0 = *(const float4*)xp;
    float4 x1 = *(const float4*)(xp + 4);
    float xs[8] = {x0.x, x0.y, x0.z, x0.w, x1.x, x1.y, x1.z, x1.w};
    bf16x8 hi, lo;
#pragma unroll
    for (int j = 0; j < 8; ++j) {
        ushort h = f2bf(xs[j]);
        hi[j] = (short)h;
        lo[j] = (short)f2bf(xs[j] - bf2f(h));
    }
    *(bf16x8*)(Xhi + (size_t)row * En + k0) = hi;
    *(bf16x8*)(Xlo + (size_t)row * En + k0) = lo;
}

// ---------------------------------------------------------------------------
// Pass 1: [Q|K|V] = X * W^T. Split 3-term MFMA, K=512. grid 3072 linear,
// XCD swizzle. z<2: write Q/K hi+lo; z==2: write vt[b][o][l] bf16.
// ---------------------------------------------------------------------------
__global__ __launch_bounds__(256) void gemm_qkv(const ushort* __restrict__ Xhi,
                                                const ushort* __restrict__ Xlo,
                                                const ushort* __restrict__ wsplit,
                                                ushort* __restrict__ Qhi, ushort* __restrict__ Qlo,
                                                ushort* __restrict__ Khi, ushort* __restrict__ Klo,
                                                ushort* __restrict__ vt) {
    const int n = blockIdx.x;
    const int xcd = n & 7;
    const int r = n >> 3;
    const int x = r % 12;
    const int y = (r / 12) * 8 + xcd;
    const int row0 = y * 128;
    const int col0 = x * 128;
    const int z = col0 >> 9;
    const int wcol = col0 & 511;

    const ushort* Whi = wsplit + (size_t)z * 2 * (En * On) + (size_t)wcol * En;
    const ushort* Wlo = Whi + En * On;

    f32x4 acc[4][4] = {};
    nt_core<true>(Xhi + (size_t)row0 * En, Xlo + (size_t)row0 * En, Whi, Wlo, En, En, En, acc);

    const int tid = threadIdx.x;
    const int lane = tid & 63, wave = tid >> 6;
    const int wr = (wave >> 1) * 64, wc = (wave & 1) * 64;
    const int ln = lane & 15;

    if (z < 2) {
        ushort* oh = (z == 0) ? Qhi : Khi;
        ushort* ol = (z == 0) ? Qlo : Klo;
#pragma unroll
        for (int m = 0; m < 4; ++m)
#pragma unroll
            for (int nn = 0; nn < 4; ++nn)
#pragma unroll
                for (int rr = 0; rr < 4; ++rr) {
                    const int gi = row0 + wr + m * 16 + (lane >> 4) * 4 + rr;
                    const int gj = wcol + wc + nn * 16 + ln;
                    const float v = acc[m][nn][rr];
                    const ushort h = f2bf(v);
                    const size_t idx = (size_t)gi * On + gj;
                    oh[idx] = h;
                    ol[idx] = f2bf(v - bf2f(h));
                }
    } else {
        const int b = row0 >> 10;
        const int lbase = row0 & (Ln - 1);
#pragma unroll
        for (int m = 0; m < 4; ++m)
#pragma unroll
            for (int nn = 0; nn < 4; ++nn) {
                const int gj = wcol + wc + nn * 16 + ln;               // o
                const int l0 = lbase + wr + m * 16 + (lane >> 4) * 4;  // l
                ushort4 u;
                u.x = f2bf(acc[m][nn][0]);
                u.y = f2bf(acc[m][nn][1]);
                u.z = f2bf(acc[m][nn][2]);
                u.w = f2bf(acc[m][nn][3]);
                *(ushort4*)(vt + ((size_t)b * On + gj) * Ln + l0) = u;
            }
    }
}

// ---------------------------------------------------------------------------
// Pass 2: S[b] = Q[b]*K[b]^T (split 3-term, K=512) + sum_k delta -> fp32
// grid 2048 linear; batch b -> XCD b%8.
// ---------------------------------------------------------------------------
__global__ __launch_bounds__(256) void gemm_scores(const ushort* __restrict__ Qhi,
                                                   const ushort* __restrict__ Qlo,
                                                   const ushort* __restrict__ Khi,
                                                   const ushort* __restrict__ Klo,
                                                   const float* __restrict__ delta,
                                                   float* __restrict__ S) {
    const int n = blockIdx.x;
    const int xcd = n & 7;
    const int c = n >> 3;
    const int b = (c / 64) * 8 + xcd;
    const int xy = c % 64;
    const int col0 = (xy & 7) * 128;
    const int row0 = (xy >> 3) * 128;

    const size_t abase = ((size_t)b * Ln + row0) * On;
    const size_t bbase = ((size_t)b * Ln + col0) * On;

    f32x4 acc[4][4] = {};
    nt_core<true>(Qhi + abase, Qlo + abase, Khi + bbase, Klo + bbase, On, On, On, acc);

    const int tid = threadIdx.x;
    const int lane = tid & 63, wave = tid >> 6;
    const int wr = (wave >> 1) * 64, wc = (wave & 1) * 64;
    const int ln = lane & 15;

#pragma unroll
    for (int m = 0; m < 4; ++m)
#pragma unroll
        for (int nn = 0; nn < 4; ++nn)
#pragma unroll
            for (int rr = 0; rr < 4; ++rr) {
                const int gi = row0 + wr + m * 16 + (lane >> 4) * 4 + rr;
                const int gj = col0 + wc + nn * 16 + ln;
                const float4 dv = *(const float4*)(delta + (((size_t)b * Ln + gi) * Ln + gj) * 4);
                S[((size_t)b * Ln + gi) * Ln + gj] = acc[m][nn][rr] + ((dv.x + dv.y) + (dv.z + dv.w));
            }
}

// ---------------------------------------------------------------------------
// Pass 3: full-row softmax (denom over ALL j), post-softmax mask,
// P written bf16 in place (first 2048B of each 4KB S row).
// ---------------------------------------------------------------------------
__global__ __launch_bounds__(256) void softmax_kernel(float* __restrict__ S,
                                                      const int* __restrict__ traj) {
    const int row = blockIdx.x;  // b*L + i
    const int b = row >> 10;
    const int i = row & (Ln - 1);
    const int t = traj[b];
    float* Srow = S + (size_t)row * Ln;
    ushort* Prow = (ushort*)Srow;
    const int tid = threadIdx.x;
    const int j0 = tid * 4;

    if (i >= t) {
        ushort4 z = {0, 0, 0, 0};
        *(ushort4*)&Prow[j0] = z;
        return;
    }

    float4 v = *(const float4*)&Srow[j0];
    __shared__ float red[4];

    float m = fmaxf(fmaxf(v.x, v.y), fmaxf(v.z, v.w));
#pragma unroll
    for (int off = 32; off >= 1; off >>= 1) m = fmaxf(m, __shfl_xor(m, off));
    if ((tid & 63) == 0) red[tid >> 6] = m;
    __syncthreads();
    m = fmaxf(fmaxf(red[0], red[1]), fmaxf(red[2], red[3]));
    __syncthreads();

    float e0 = expf(v.x - m), e1 = expf(v.y - m), e2 = expf(v.z - m), e3 = expf(v.w - m);
    float s = (e0 + e1) + (e2 + e3);
#pragma unroll
    for (int off = 32; off >= 1; off >>= 1) s += __shfl_xor(s, off);
    if ((tid & 63) == 0) red[tid >> 6] = s;
    __syncthreads();
    s = (red[0] + red[1]) + (red[2] + red[3]);
    const float inv = 1.0f / s;

    ushort4 o;
    o.x = (j0 + 0 < t) ? f2bf(e0 * inv) : (ushort)0;
    o.y = (j0 + 1 < t) ? f2bf(e1 * inv) : (ushort)0;
    o.z = (j0 + 2 < t) ? f2bf(e2 * inv) : (ushort)0;
    o.w = (j0 + 3 < t) ? f2bf(e3 * inv) : (ushort)0;
    *(ushort4*)&Prow[j0] = o;
}

// ---------------------------------------------------------------------------
// Pass 4: out[b] = P[b] (bf16, row stride 2048) * V[b]  (plain bf16, K=1024)
// grid 1024 linear; batch b -> XCD b%8.
// ---------------------------------------------------------------------------
__global__ __launch_bounds__(256) void gemm_pv(const ushort* __restrict__ P,
                                               const ushort* __restrict__ vt,
                                               float* __restrict__ out) {
    const int n = blockIdx.x;
    const int xcd = n & 7;
    const int c = n >> 3;
    const int b = (c / 32) * 8 + xcd;
    const int xy = c % 32;
    const int col0 = (xy & 3) * 128;
    const int row0 = (xy >> 2) * 128;

    f32x4 acc[4][4] = {};
    nt_core<false>(P + ((size_t)b * Ln + row0) * 2048, nullptr,
                   vt + ((size_t)b * On + col0) * Ln, nullptr, 2048, Ln, Ln, acc);

    const int tid = threadIdx.x;
    const int lane = tid & 63, wave = tid >> 6;
    const int wr = (wave >> 1) * 64, wc = (wave & 1) * 64;
    const int ln = lane & 15;

#pragma unroll
    for (int m = 0; m < 4; ++m)
#pragma unroll
        for (int nn = 0; nn < 4; ++nn)
#pragma unroll
            for (int rr = 0; rr < 4; ++rr) {
                const int gi = row0 + wr + m * 16 + (lane >> 4) * 4 + rr;
                const int gj = col0 + wc + nn * 16 + ln;
                out[((size_t)b * Ln + gi) * On + gj] = acc[m][nn][rr];
            }
}

extern "C" void kernel_launch(void* const* d_in, const int* in_sizes, int n_in,
                              void* d_out, int out_size, void* d_ws, size_t ws_size,
                              hipStream_t stream) {
    const float* X = (const float*)d_in[0];      // [B, L, E]
    const float* delta = (const float*)d_in[1];  // [B, L, L, 4]
    const float* Wq = (const float*)d_in[2];     // [E, O]
    const float* Wk = (const float*)d_in[3];
    const float* Wv = (const float*)d_in[4];
    const int* traj = (const int*)d_in[5];       // [B]
    float* out = (float*)d_out;

    // ws layout (ushort units unless noted)
    const size_t NE = (size_t)Bn * Ln * On;  // 16.77M elements
    ushort* wsplit = (ushort*)d_ws;          // 3*2*En*On = 1.57M shorts
    ushort* Xhi = wsplit + (size_t)3 * 2 * En * On;
    ushort* Xlo = Xhi + NE;
    ushort* Qhi = Xlo + NE;
    ushort* Qlo = Qhi + NE;
    ushort* Khi = Qlo + NE;
    ushort* Klo = Khi + NE;
    ushort* vt = Klo + NE;                   // [B][O][L]
    float* S = (float*)(vt + NE);            // [B][L][L] fp32 / P bf16 in place

    convert_w<<<dim3(On / 32, En / 32, 3), 256, 0, stream>>>(Wq, Wk, Wv, wsplit);
    convert_x<<<dim3((Bn * Ln * 64) / 256), 256, 0, stream>>>(X, Xhi, Xlo);
    gemm_qkv<<<dim3(3072), 256, 0, stream>>>(Xhi, Xlo, wsplit, Qhi, Qlo, Khi, Klo, vt);
    gemm_scores<<<dim3(2048), 256, 0, stream>>>(Qhi, Qlo, Khi, Klo, delta, S);
    softmax_kernel<<<dim3(Bn * Ln), 256, 0, stream>>>(S, traj);
    gemm_pv<<<dim3(1024), 256, 0, stream>>>((const ushort*)S, vt, out);
}

// Round 6
// 457.914 us; speedup vs baseline: 1.4850x; 1.1131x over previous
//
#include <hip/hip_runtime.h>
#include <hip/hip_bf16.h>

#define Bn 32
#define Ln 1024
#define En 512
#define On 512

typedef __attribute__((ext_vector_type(8))) short bf16x8;
typedef __attribute__((ext_vector_type(4))) float f32x4;

__device__ __forceinline__ ushort f2bf(float x) {
    __hip_bfloat16 h = __float2bfloat16(x);
    return *reinterpret_cast<ushort*>(&h);
}
__device__ __forceinline__ float bf2f(ushort u) {
    __hip_bfloat16 h;
    *reinterpret_cast<ushort*>(&h) = u;
    return __bfloat162float(h);
}

__device__ __forceinline__ f32x4 mfma_bf16(bf16x8 a, bf16x8 b, f32x4 c) {
    return __builtin_amdgcn_mfma_f32_16x16x32_bf16(a, b, c, 0, 0, 0);
}

// ---------------------------------------------------------------------------
// Stage a 128x32 bf16 tile (row stride `rstride` shorts) into linear LDS
// [128][32] via global_load_lds width=16. 256 threads * 2 issues * 16B = 8KB.
// ---------------------------------------------------------------------------
__device__ __forceinline__ void stage(ushort* dst, const ushort* src, size_t rstride) {
    const int tid = threadIdx.x;
#pragma unroll
    for (int cc = 0; cc < 2; ++cc) {
        const int c = tid + cc * 256;
        const ushort* g = src + (size_t)(c >> 2) * rstride + (c & 3) * 8;
        ushort* l = dst + ((size_t)(tid >> 6) * 64 + cc * 256) * 8;
        __builtin_amdgcn_global_load_lds(
            (const __attribute__((address_space(1))) unsigned int*)g,
            (__attribute__((address_space(3))) unsigned int*)l, 16, 0, 0);
    }
}

// ---------------------------------------------------------------------------
// Pipelined NT bf16 GEMM core, 128x128 tile, BK=32, 256 threads (4 waves 2x2).
// Double-buffered LDS + COUNTED vmcnt (never 0 in steady state), raw
// s_barrier (no __syncthreads -> no compiler vmcnt(0) drain).
// Schedule (provable): prologue stages K0->slot0, K1->slot1, vmcnt(LOADS)
// waits K0 only. Iter t: compute slot t&1; lgkmcnt(0)+barrier (slot free);
// stage K(t+2) into freed slot; vmcnt(LOADS) waits K(t+1) (K(t+2) stays in
// flight); barrier. Invariant: after iter t's last barrier, tiles <= t+1
// are globally staged.
// SPLIT: acc += Ah*Bh + Ah*Bl + Al*Bh (compensated product).
// ---------------------------------------------------------------------------
template <bool SPLIT>
__device__ __forceinline__ void nt_core_pipe(const ushort* __restrict__ Ah,
                                             const ushort* __restrict__ Al,
                                             const ushort* __restrict__ Bh,
                                             const ushort* __restrict__ Bl,
                                             size_t astr, size_t bstr, int Kd,
                                             f32x4 (&acc)[4][4]) {
    constexpr int NTL = SPLIT ? 4 : 2;    // tiles per K-step
    constexpr int LOADS = SPLIT ? 8 : 4;  // gload_lds issues per thread per K-step
    __shared__ ushort lds[2][NTL * 4096];

    const int tid = threadIdx.x;
    const int lane = tid & 63, wave = tid >> 6;
    const int wr = (wave >> 1) * 64, wc = (wave & 1) * 64;
    const int ln = lane & 15, kb = (lane >> 4) * 8;
    const int NT = Kd >> 5;  // K-tiles of 32 (>= 16 for all our shapes)

    auto stage_all = [&](int kt, int slot) {
        const int k0 = kt * 32;
        stage(&lds[slot][0], Ah + k0, astr);
        stage(&lds[slot][4096], Bh + k0, bstr);
        if constexpr (SPLIT) {
            stage(&lds[slot][8192], Al + k0, astr);
            stage(&lds[slot][12288], Bl + k0, bstr);
        }
    };

    stage_all(0, 0);
    stage_all(1, 1);
    asm volatile("s_waitcnt vmcnt(%0)" ::"i"(LOADS) : "memory");
    __builtin_amdgcn_sched_barrier(0);
    __builtin_amdgcn_s_barrier();

    for (int t = 0; t < NT; ++t) {
        __builtin_amdgcn_sched_barrier(0);
        const int cur = t & 1;
        const ushort* sAh = &lds[cur][0];
        const ushort* sBh = &lds[cur][4096];

        bf16x8 bh[4], bl[4];
#pragma unroll
        for (int n = 0; n < 4; ++n) {
            bh[n] = *(const bf16x8*)&sBh[(size_t)(wc + n * 16 + ln) * 32 + kb];
            if constexpr (SPLIT)
                bl[n] = *(const bf16x8*)&lds[cur][12288 + (size_t)(wc + n * 16 + ln) * 32 + kb];
        }
#pragma unroll
        for (int m = 0; m < 4; ++m) {
            bf16x8 ah = *(const bf16x8*)&sAh[(size_t)(wr + m * 16 + ln) * 32 + kb];
            if constexpr (SPLIT) {
                bf16x8 al = *(const bf16x8*)&lds[cur][8192 + (size_t)(wr + m * 16 + ln) * 32 + kb];
#pragma unroll
                for (int n = 0; n < 4; ++n) {
                    acc[m][n] = mfma_bf16(ah, bh[n], acc[m][n]);
                    acc[m][n] = mfma_bf16(ah, bl[n], acc[m][n]);
                    acc[m][n] = mfma_bf16(al, bh[n], acc[m][n]);
                }
            } else {
#pragma unroll
                for (int n = 0; n < 4; ++n) acc[m][n] = mfma_bf16(ah, bh[n], acc[m][n]);
            }
        }

        asm volatile("s_waitcnt lgkmcnt(0)" ::: "memory");
        __builtin_amdgcn_sched_barrier(0);
        __builtin_amdgcn_s_barrier();  // all waves done reading slot cur

        if (t + 2 < NT) {
            stage_all(t + 2, cur);  // overwrite freed slot; stays in flight
            asm volatile("s_waitcnt vmcnt(%0)" ::"i"(LOADS) : "memory");
            __builtin_amdgcn_sched_barrier(0);
            __builtin_amdgcn_s_barrier();  // K(t+1) globally ready
        } else if (t + 1 < NT) {
            asm volatile("s_waitcnt vmcnt(0)" ::: "memory");
            __builtin_amdgcn_sched_barrier(0);
            __builtin_amdgcn_s_barrier();
        }
    }
}

// ---------------------------------------------------------------------------
// W [E,O] fp32 -> per z: whi/wlo [n][k] bf16 (transposed), stride En.
// ---------------------------------------------------------------------------
__global__ __launch_bounds__(256) void convert_w(const float* __restrict__ Wq,
                                                 const float* __restrict__ Wk,
                                                 const float* __restrict__ Wv,
                                                 ushort* __restrict__ wsplit) {
    const int z = blockIdx.z;
    const float* W = (z == 0) ? Wq : (z == 1) ? Wk : Wv;
    ushort* hi = wsplit + (size_t)z * 2 * (En * On);
    ushort* lo = hi + En * On;
    __shared__ float tile[32][33];
    const int n0 = blockIdx.x * 32, k0 = blockIdx.y * 32;
    const int tid = threadIdx.x;
    const int r = tid >> 3, c4 = (tid & 7) * 4;
    float4 wv = *(const float4*)&W[(size_t)(k0 + r) * On + n0 + c4];
    tile[r][c4 + 0] = wv.x;
    tile[r][c4 + 1] = wv.y;
    tile[r][c4 + 2] = wv.z;
    tile[r][c4 + 3] = wv.w;
    __syncthreads();
    ushort4 hs, ls;
    ushort* hp = &hs.x;
    ushort* lp = &ls.x;
#pragma unroll
    for (int jj = 0; jj < 4; ++jj) {
        float f = tile[c4 + jj][r];
        ushort h = f2bf(f);
        hp[jj] = h;
        lp[jj] = f2bf(f - bf2f(h));
    }
    *(ushort4*)&hi[(size_t)(n0 + r) * En + k0 + c4] = hs;
    *(ushort4*)&lo[(size_t)(n0 + r) * En + k0 + c4] = ls;
}

// ---------------------------------------------------------------------------
// X [32768, 512] fp32 -> Xhi / Xlo [32768, 512] bf16
// ---------------------------------------------------------------------------
__global__ __launch_bounds__(256) void convert_x(const float* __restrict__ X,
                                                 ushort* __restrict__ Xhi,
                                                 ushort* __restrict__ Xlo) {
    const int g = blockIdx.x * 256 + threadIdx.x;
    const int row = g >> 6;
    const int k0 = (g & 63) * 8;
    const float* xp = X + (size_t)row * En + k0;
    float4 x0 = *(const float4*)xp;
    float4 x1 = *(const float4*)(xp + 4);
    float xs[8] = {x0.x, x0.y, x0.z, x0.w, x1.x, x1.y, x1.z, x1.w};
    bf16x8 hi, lo;
#pragma unroll
    for (int j = 0; j < 8; ++j) {
        ushort h = f2bf(xs[j]);
        hi[j] = (short)h;
        lo[j] = (short)f2bf(xs[j] - bf2f(h));
    }
    *(bf16x8*)(Xhi + (size_t)row * En + k0) = hi;
    *(bf16x8*)(Xlo + (size_t)row * En + k0) = lo;
}

// ---------------------------------------------------------------------------
// Pass 1a: Q,K = X * W^T. Split 3-term MFMA, K=512. grid 2048 linear,
// XCD swizzle. Writes Q/K hi+lo.
// ---------------------------------------------------------------------------
__global__ __launch_bounds__(256) void gemm_qkv(const ushort* __restrict__ Xhi,
                                                const ushort* __restrict__ Xlo,
                                                const ushort* __restrict__ wsplit,
                                                ushort* __restrict__ Qhi, ushort* __restrict__ Qlo,
                                                ushort* __restrict__ Khi, ushort* __restrict__ Klo) {
    const int n = blockIdx.x;
    const int xcd = n & 7;
    const int r = n >> 3;
    const int x = r & 7;
    const int y = (r >> 3) * 8 + xcd;
    const int row0 = y * 128;
    const int col0 = x * 128;
    const int z = col0 >> 9;  // 0 -> Q, 1 -> K
    const int wcol = col0 & 511;

    const ushort* Whi = wsplit + (size_t)z * 2 * (En * On) + (size_t)wcol * En;
    const ushort* Wlo = Whi + En * On;

    f32x4 acc[4][4] = {};
    nt_core_pipe<true>(Xhi + (size_t)row0 * En, Xlo + (size_t)row0 * En, Whi, Wlo, En, En, En, acc);

    const int tid = threadIdx.x;
    const int lane = tid & 63, wave = tid >> 6;
    const int wr = (wave >> 1) * 64, wc = (wave & 1) * 64;
    const int ln = lane & 15;

    ushort* oh = (z == 0) ? Qhi : Khi;
    ushort* ol = (z == 0) ? Qlo : Klo;
#pragma unroll
    for (int m = 0; m < 4; ++m)
#pragma unroll
        for (int nn = 0; nn < 4; ++nn)
#pragma unroll
            for (int rr = 0; rr < 4; ++rr) {
                const int gi = row0 + wr + m * 16 + (lane >> 4) * 4 + rr;
                const int gj = wcol + wc + nn * 16 + ln;
                const float v = acc[m][nn][rr];
                const ushort h = f2bf(v);
                const size_t idx = (size_t)gi * On + gj;
                oh[idx] = h;
                ol[idx] = f2bf(v - bf2f(h));
            }
}

// ---------------------------------------------------------------------------
// Pass 1b: V = X * Wv^T, PLAIN bf16 (V feeds bf16 PV anyway). grid 1024.
// Writes vt[b][o][l] bf16 (transposed for PV's B operand).
// ---------------------------------------------------------------------------
__global__ __launch_bounds__(256) void gemm_v(const ushort* __restrict__ Xhi,
                                              const ushort* __restrict__ wsplit,
                                              ushort* __restrict__ vt) {
    const int n = blockIdx.x;
    const int xcd = n & 7;
    const int c = n >> 3;
    const int x = c & 3;
    const int y = (c >> 2) * 8 + xcd;
    const int row0 = y * 128;
    const int col0 = x * 128;

    const ushort* Whi = wsplit + (size_t)2 * 2 * (En * On) + (size_t)col0 * En;  // z=2 hi slab

    f32x4 acc[4][4] = {};
    nt_core_pipe<false>(Xhi + (size_t)row0 * En, nullptr, Whi, nullptr, En, En, En, acc);

    const int tid = threadIdx.x;
    const int lane = tid & 63, wave = tid >> 6;
    const int wr = (wave >> 1) * 64, wc = (wave & 1) * 64;
    const int ln = lane & 15;

    const int b = row0 >> 10;
    const int lbase = row0 & (Ln - 1);
#pragma unroll
    for (int m = 0; m < 4; ++m)
#pragma unroll
        for (int nn = 0; nn < 4; ++nn) {
            const int gj = col0 + wc + nn * 16 + ln;               // o
            const int l0 = lbase + wr + m * 16 + (lane >> 4) * 4;  // l
            ushort4 u;
            u.x = f2bf(acc[m][nn][0]);
            u.y = f2bf(acc[m][nn][1]);
            u.z = f2bf(acc[m][nn][2]);
            u.w = f2bf(acc[m][nn][3]);
            *(ushort4*)(vt + ((size_t)b * On + gj) * Ln + l0) = u;
        }
}

// ---------------------------------------------------------------------------
// Pass 2: S[b] = Q[b]*K[b]^T (split 3-term, K=512) + sum_k delta -> fp32
// grid 2048 linear; batch b -> XCD b%8.
// ---------------------------------------------------------------------------
__global__ __launch_bounds__(256) void gemm_scores(const ushort* __restrict__ Qhi,
                                                   const ushort* __restrict__ Qlo,
                                                   const ushort* __restrict__ Khi,
                                                   const ushort* __restrict__ Klo,
                                                   const float* __restrict__ delta,
                                                   float* __restrict__ S) {
    const int n = blockIdx.x;
    const int xcd = n & 7;
    const int c = n >> 3;
    const int b = (c / 64) * 8 + xcd;
    const int xy = c % 64;
    const int col0 = (xy & 7) * 128;
    const int row0 = (xy >> 3) * 128;

    const size_t abase = ((size_t)b * Ln + row0) * On;
    const size_t bbase = ((size_t)b * Ln + col0) * On;

    f32x4 acc[4][4] = {};
    nt_core_pipe<true>(Qhi + abase, Qlo + abase, Khi + bbase, Klo + bbase, On, On, On, acc);

    const int tid = threadIdx.x;
    const int lane = tid & 63, wave = tid >> 6;
    const int wr = (wave >> 1) * 64, wc = (wave & 1) * 64;
    const int ln = lane & 15;

#pragma unroll
    for (int m = 0; m < 4; ++m)
#pragma unroll
        for (int nn = 0; nn < 4; ++nn)
#pragma unroll
            for (int rr = 0; rr < 4; ++rr) {
                const int gi = row0 + wr + m * 16 + (lane >> 4) * 4 + rr;
                const int gj = col0 + wc + nn * 16 + ln;
                const float4 dv = *(const float4*)(delta + (((size_t)b * Ln + gi) * Ln + gj) * 4);
                S[((size_t)b * Ln + gi) * Ln + gj] = acc[m][nn][rr] + ((dv.x + dv.y) + (dv.z + dv.w));
            }
}

// ---------------------------------------------------------------------------
// Pass 3: full-row softmax (denom over ALL j), post-softmax mask,
// P written bf16 in place (first 2048B of each 4KB S row).
// ---------------------------------------------------------------------------
__global__ __launch_bounds__(256) void softmax_kernel(float* __restrict__ S,
                                                      const int* __restrict__ traj) {
    const int row = blockIdx.x;  // b*L + i
    const int b = row >> 10;
    const int i = row & (Ln - 1);
    const int t = traj[b];
    float* Srow = S + (size_t)row * Ln;
    ushort* Prow = (ushort*)Srow;
    const int tid = threadIdx.x;
    const int j0 = tid * 4;

    if (i >= t) {
        ushort4 z = {0, 0, 0, 0};
        *(ushort4*)&Prow[j0] = z;
        return;
    }

    float4 v = *(const float4*)&Srow[j0];
    __shared__ float red[4];

    float m = fmaxf(fmaxf(v.x, v.y), fmaxf(v.z, v.w));
#pragma unroll
    for (int off = 32; off >= 1; off >>= 1) m = fmaxf(m, __shfl_xor(m, off));
    if ((tid & 63) == 0) red[tid >> 6] = m;
    __syncthreads();
    m = fmaxf(fmaxf(red[0], red[1]), fmaxf(red[2], red[3]));
    __syncthreads();

    float e0 = expf(v.x - m), e1 = expf(v.y - m), e2 = expf(v.z - m), e3 = expf(v.w - m);
    float s = (e0 + e1) + (e2 + e3);
#pragma unroll
    for (int off = 32; off >= 1; off >>= 1) s += __shfl_xor(s, off);
    if ((tid & 63) == 0) red[tid >> 6] = s;
    __syncthreads();
    s = (red[0] + red[1]) + (red[2] + red[3]);
    const float inv = 1.0f / s;

    ushort4 o;
    o.x = (j0 + 0 < t) ? f2bf(e0 * inv) : (ushort)0;
    o.y = (j0 + 1 < t) ? f2bf(e1 * inv) : (ushort)0;
    o.z = (j0 + 2 < t) ? f2bf(e2 * inv) : (ushort)0;
    o.w = (j0 + 3 < t) ? f2bf(e3 * inv) : (ushort)0;
    *(ushort4*)&Prow[j0] = o;
}

// ---------------------------------------------------------------------------
// Pass 4: out[b] = P[b] (bf16, row stride 2048) * V[b]  (plain bf16, K=1024)
// grid 1024 linear; batch b -> XCD b%8.
// ---------------------------------------------------------------------------
__global__ __launch_bounds__(256) void gemm_pv(const ushort* __restrict__ P,
                                               const ushort* __restrict__ vt,
                                               float* __restrict__ out) {
    const int n = blockIdx.x;
    const int xcd = n & 7;
    const int c = n >> 3;
    const int b = (c / 32) * 8 + xcd;
    const int xy = c % 32;
    const int col0 = (xy & 3) * 128;
    const int row0 = (xy >> 2) * 128;

    f32x4 acc[4][4] = {};
    nt_core_pipe<false>(P + ((size_t)b * Ln + row0) * 2048, nullptr,
                        vt + ((size_t)b * On + col0) * Ln, nullptr, 2048, Ln, Ln, acc);

    const int tid = threadIdx.x;
    const int lane = tid & 63, wave = tid >> 6;
    const int wr = (wave >> 1) * 64, wc = (wave & 1) * 64;
    const int ln = lane & 15;

#pragma unroll
    for (int m = 0; m < 4; ++m)
#pragma unroll
        for (int nn = 0; nn < 4; ++nn)
#pragma unroll
            for (int rr = 0; rr < 4; ++rr) {
                const int gi = row0 + wr + m * 16 + (lane >> 4) * 4 + rr;
                const int gj = col0 + wc + nn * 16 + ln;
                out[((size_t)b * Ln + gi) * On + gj] = acc[m][nn][rr];
            }
}

extern "C" void kernel_launch(void* const* d_in, const int* in_sizes, int n_in,
                              void* d_out, int out_size, void* d_ws, size_t ws_size,
                              hipStream_t stream) {
    const float* X = (const float*)d_in[0];      // [B, L, E]
    const float* delta = (const float*)d_in[1];  // [B, L, L, 4]
    const float* Wq = (const float*)d_in[2];     // [E, O]
    const float* Wk = (const float*)d_in[3];
    const float* Wv = (const float*)d_in[4];
    const int* traj = (const int*)d_in[5];       // [B]
    float* out = (float*)d_out;

    // ws layout (ushort units unless noted)
    const size_t NE = (size_t)Bn * Ln * On;  // 16.77M elements
    ushort* wsplit = (ushort*)d_ws;          // 3*2*En*On
    ushort* Xhi = wsplit + (size_t)3 * 2 * En * On;
    ushort* Xlo = Xhi + NE;
    ushort* Qhi = Xlo + NE;
    ushort* Qlo = Qhi + NE;
    ushort* Khi = Qlo + NE;
    ushort* Klo = Khi + NE;
    ushort* vt = Klo + NE;                   // [B][O][L]
    float* S = (float*)(vt + NE);            // [B][L][L] fp32 / P bf16 in place

    convert_w<<<dim3(On / 32, En / 32, 3), 256, 0, stream>>>(Wq, Wk, Wv, wsplit);
    convert_x<<<dim3((Bn * Ln * 64) / 256), 256, 0, stream>>>(X, Xhi, Xlo);
    gemm_qkv<<<dim3(2048), 256, 0, stream>>>(Xhi, Xlo, wsplit, Qhi, Qlo, Khi, Klo);
    gemm_v<<<dim3(1024), 256, 0, stream>>>(Xhi, wsplit, vt);
    gemm_scores<<<dim3(2048), 256, 0, stream>>>(Qhi, Qlo, Khi, Klo, delta, S);
    softmax_kernel<<<dim3(Bn * Ln), 256, 0, stream>>>(S, traj);
    gemm_pv<<<dim3(1024), 256, 0, stream>>>((const ushort*)S, vt, out);
}